// Round 1
// baseline (192.015 us; speedup 1.0000x reference)
//
#include <hip/hip_runtime.h>
#include <hip/hip_bf16.h>
#include <stdint.h>

// PatchedVisionExpertMLP — round 17
//   r16 baseline: 181.6us; gemm_p1 = 81us at MfmaUtil 38% (m97-structure ceiling).
//   This round: gemm_p1 rewritten as phase-split counted-vmcnt schedule (T3+T4+T5):
//   128 A-rows x (128 gate | 128 up) B-rows per block, 8 waves, 96 KiB LDS dbuf,
//   2 phases/K-tile x 16 MFMA, 2-tile prefetch lookahead, steady-state vmcnt(4)
//   (never 0), setprio(1) around MFMA. Everything else frozen (scan pad stays 128).

#define TOKENS 4096
#define SEQ    2048
#define DIM    1024
#define FFDIM  4096
#define MAXPAD 4608

typedef __attribute__((ext_vector_type(8))) short bf16x8;
typedef __attribute__((ext_vector_type(4))) float f32x4;

#define GAS __attribute__((address_space(1)))
#define LAS __attribute__((address_space(3)))

__device__ inline unsigned short f2bf(float x) {
    union { float f; unsigned int u; } c; c.f = x;
    unsigned int r = c.u + 0x7FFFu + ((c.u >> 16) & 1u);  // RNE
    return (unsigned short)(r >> 16);
}
__device__ inline float bf2f(unsigned short u) {
    union { unsigned int i; float f; } c; c.i = ((unsigned int)u) << 16;
    return c.f;
}

struct __align__(16) us8 { unsigned short v[8]; };

// ---------- scan: group tokens by expert, pad each segment to 128 ----------
__global__ __launch_bounds__(1024) void scan_kernel(const int* __restrict__ tt,
                                                    int* __restrict__ src_of,
                                                    int* __restrict__ counts) {
    __shared__ int sc[1024];
    const int tid = threadIdx.x;
    for (int i = tid; i < MAXPAD; i += 1024) src_of[i] = -1;

    const int t0 = tid * 4;
    int v[4], cnt = 0;
#pragma unroll
    for (int j = 0; j < 4; ++j) {
        const int t = t0 + j;
        const int l = t & (SEQ - 1);
        int vis = 0;
        if (l < SEQ - 1) vis = (tt[t] == 1) & (tt[t + 1] == 1);
        v[j] = vis; cnt += vis;
    }
    sc[tid] = cnt;
    __syncthreads();
    for (int off = 1; off < 1024; off <<= 1) {
        const int val = sc[tid];
        const int add = (tid >= off) ? sc[tid - off] : 0;
        __syncthreads();
        sc[tid] = val + add;
        __syncthreads();
    }
    const int totalV = sc[1023];
    const int excl   = sc[tid] - cnt;
    const int padNv  = (totalV + 127) & ~127;
    int pv = excl;
    int pl = padNv + (t0 - excl);
#pragma unroll
    for (int j = 0; j < 4; ++j) {
        const int t = t0 + j;
        if (v[j]) src_of[pv++] = t; else src_of[pl++] = t;
    }
    if (tid == 0) {
        const int Nl = TOKENS - totalV;
        counts[0] = padNv;
        counts[1] = padNv + ((Nl + 127) & ~127);
    }
}

__global__ void gather_cast(const float* __restrict__ hs, const int* __restrict__ src_of,
                            unsigned short* __restrict__ Xg) {
    const int gid = blockIdx.x * 256 + threadIdx.x;
    const int row = gid >> 7;
    const int c   = (gid & 127) * 8;
    const int src = src_of[row];
    us8 o;
    if (src >= 0) {
        const float4 a = *reinterpret_cast<const float4*>(hs + (size_t)src * DIM + c);
        const float4 b = *reinterpret_cast<const float4*>(hs + (size_t)src * DIM + c + 4);
        o.v[0] = f2bf(a.x); o.v[1] = f2bf(a.y); o.v[2] = f2bf(a.z); o.v[3] = f2bf(a.w);
        o.v[4] = f2bf(b.x); o.v[5] = f2bf(b.y); o.v[6] = f2bf(b.z); o.v[7] = f2bf(b.w);
    } else {
#pragma unroll
        for (int j = 0; j < 8; ++j) o.v[j] = 0;
    }
    *reinterpret_cast<us8*>(Xg + (size_t)row * DIM + c) = o;
}

__device__ inline void cast8(const float* __restrict__ in, unsigned short* __restrict__ out, int i) {
    const float4 a = *reinterpret_cast<const float4*>(in + i);
    const float4 b = *reinterpret_cast<const float4*>(in + i + 4);
    us8 o;
    o.v[0] = f2bf(a.x); o.v[1] = f2bf(a.y); o.v[2] = f2bf(a.z); o.v[3] = f2bf(a.w);
    o.v[4] = f2bf(b.x); o.v[5] = f2bf(b.y); o.v[6] = f2bf(b.z); o.v[7] = f2bf(b.w);
    *reinterpret_cast<us8*>(out + i) = o;
}

__global__ void cast6_kernel(const float* __restrict__ s0, const float* __restrict__ s1,
                             const float* __restrict__ s2, const float* __restrict__ s3,
                             const float* __restrict__ s4, const float* __restrict__ s5,
                             unsigned short* __restrict__ d0, unsigned short* __restrict__ d1,
                             unsigned short* __restrict__ d2, unsigned short* __restrict__ d3,
                             unsigned short* __restrict__ d4, unsigned short* __restrict__ d5) {
    const int i = (blockIdx.x * 256 + threadIdx.x) * 8;
    const int m = blockIdx.y;
    const float* s = (m == 0) ? s0 : (m == 1) ? s1 : (m == 2) ? s2 : (m == 3) ? s3 : (m == 4) ? s4 : s5;
    unsigned short* d = (m == 0) ? d0 : (m == 1) ? d1 : (m == 2) ? d2 : (m == 3) ? d3 : (m == 4) ? d4 : d5;
    cast8(s, d, i);
}

__global__ void cast4_kernel(const float* __restrict__ s0, const float* __restrict__ s1,
                             const float* __restrict__ s2, const float* __restrict__ s3,
                             unsigned short* __restrict__ d0, unsigned short* __restrict__ d1,
                             unsigned short* __restrict__ d2, unsigned short* __restrict__ d3) {
    const int i = (blockIdx.x * 256 + threadIdx.x) * 8;
    const int m = blockIdx.y;
    const float* s = (m == 0) ? s0 : (m == 1) ? s1 : (m == 2) ? s2 : s3;
    unsigned short* d = (m == 0) ? d0 : (m == 1) ? d1 : (m == 2) ? d2 : d3;
    cast8(s, d, i);
}

__global__ void cast2_kernel(const float* __restrict__ s0, const float* __restrict__ s1,
                             unsigned short* __restrict__ d0, unsigned short* __restrict__ d1) {
    const int i = (blockIdx.x * 256 + threadIdx.x) * 8;
    const float* s = blockIdx.y ? s1 : s0;
    unsigned short* d = blockIdx.y ? d1 : d0;
    cast8(s, d, i);
}

// ========== PHASE 1: 128row x (128 gate | 128 up) phase-split counted-vmcnt ==========
// 8 waves (2M x 4N), per-wave 64x32 output. LDS rows: A 0..127, G 128..255, U 256..383.
// Per K-tile (BK=64): ph0 = gate half (16 MFMA), ph1 = up half (16 MFMA).
// Prefetch: t.ph0 stages U(t+1) -> other buf; t.ph1 stages A+G(t+2) -> current buf
// (A,G regions dead after t.ph0), then s_waitcnt vmcnt(4) — never 0 in steady state.
__global__ __launch_bounds__(512, 2) void gemm_p1(
    const unsigned short* __restrict__ A,
    const unsigned short* __restrict__ B0_v, const unsigned short* __restrict__ B1_v,
    const unsigned short* __restrict__ B0_l, const unsigned short* __restrict__ B1_l,
    unsigned short* __restrict__ H,
    const int* __restrict__ counts)
{
    __shared__ unsigned short Ls[2][384 * 64];   // 96 KiB

    const int m0 = blockIdx.y * 128;
    const int padNv = counts[0], padTot = counts[1];
    if (m0 >= padTot) return;
    const int expert = (m0 >= padNv);
    const unsigned short* Wg = expert ? B0_l : B0_v;
    const unsigned short* Wu = expert ? B1_l : B1_v;

    const int tid  = threadIdx.x;
    const int wid  = tid >> 6;     // 0..7
    const int lane = tid & 63;
    const int wr   = wid >> 2;     // 0..1 : 64-row half
    const int wc   = wid & 3;      // 0..3 : 32-col quarter
    const int n0   = blockIdx.x * 128;

    // staging: pre-swizzled global source, linear LDS dest (both-sides-or-neither)
    const int cs   = ((lane & 7) ^ (lane >> 3)) * 8;
    const int grow = wid * 8 + (lane >> 3);      // 0..63

    const unsigned short* pA0 = A  + (size_t)(m0 + grow) * DIM + cs;
    const unsigned short* pA1 = A  + (size_t)(m0 + 64 + grow) * DIM + cs;
    const unsigned short* pG0 = Wg + (size_t)(n0 + grow) * DIM + cs;
    const unsigned short* pG1 = Wg + (size_t)(n0 + 64 + grow) * DIM + cs;
    const unsigned short* pU0 = Wu + (size_t)(n0 + grow) * DIM + cs;
    const unsigned short* pU1 = Wu + (size_t)(n0 + 64 + grow) * DIM + cs;

    const int dA0 = (      wid * 8) * 64;        // wave-uniform LDS dests (shorts)
    const int dA1 = ( 64 + wid * 8) * 64;
    const int dG0 = (128 + wid * 8) * 64;
    const int dG1 = (192 + wid * 8) * 64;
    const int dU0 = (256 + wid * 8) * 64;
    const int dU1 = (320 + wid * 8) * 64;

#define GLD(p, L, d) __builtin_amdgcn_global_load_lds((const GAS void*)(p), (LAS void*)((L) + (d)), 16, 0, 0)
#define ST_AG(L, ko) do { GLD(pA0 + (ko), L, dA0); GLD(pA1 + (ko), L, dA1); \
                          GLD(pG0 + (ko), L, dG0); GLD(pG1 + (ko), L, dG1); } while (0)
#define ST_U(L, ko)  do { GLD(pU0 + (ko), L, dU0); GLD(pU1 + (ko), L, dU1); } while (0)

    unsigned short* L0 = &Ls[0][0];
    unsigned short* L1 = &Ls[1][0];

    f32x4 acc[4][4];
#pragma unroll
    for (int i = 0; i < 4; ++i)
#pragma unroll
        for (int j = 0; j < 4; ++j)
            acc[i][j] = (f32x4){0.f, 0.f, 0.f, 0.f};

    // prologue: tile0 full (A,G,U) into buf0; A,G of tile1 into buf1; leave the 4
    // newest (A,G of tile1) in flight.
    ST_AG(L0, 0);
    ST_U (L0, 0);
    ST_AG(L1, 64);
    asm volatile("s_waitcnt vmcnt(4)" ::: "memory");
    asm volatile("" ::: "memory");
    __builtin_amdgcn_s_barrier();
    asm volatile("" ::: "memory");

    const int rlo = lane & 15;
    const int sw7 = rlo & 7;
    bf16x8 af[4][2], bg[2][2], bu[2][2];

    const int NKT = DIM / 64;   // 16
#pragma unroll 2
    for (int kt = 0; kt < NKT; ++kt) {
        unsigned short* Lc = (kt & 1) ? L1 : L0;
        unsigned short* Ln = (kt & 1) ? L0 : L1;

        // ---------- phase 0 : gate half ----------
#pragma unroll
        for (int kh = 0; kh < 2; ++kh) {
            const int swoff = (((lane >> 4) + kh * 4) ^ sw7) * 8;
#pragma unroll
            for (int i = 0; i < 4; ++i)
                af[i][kh] = *reinterpret_cast<const bf16x8*>(&Lc[(wr * 64 + i * 16 + rlo) * 64 + swoff]);
#pragma unroll
            for (int j = 0; j < 2; ++j)
                bg[j][kh] = *reinterpret_cast<const bf16x8*>(&Lc[(128 + wc * 32 + j * 16 + rlo) * 64 + swoff]);
        }
        if (kt + 1 < NKT) ST_U(Ln, (kt + 1) * 64);
        asm volatile("" ::: "memory");
        __builtin_amdgcn_s_barrier();
        asm volatile("s_waitcnt lgkmcnt(0)" ::: "memory");
        __builtin_amdgcn_s_setprio(1);
#pragma unroll
        for (int kh = 0; kh < 2; ++kh)
#pragma unroll
            for (int i = 0; i < 4; ++i)
#pragma unroll
                for (int j = 0; j < 2; ++j)
                    acc[i][j] = __builtin_amdgcn_mfma_f32_16x16x32_bf16(af[i][kh], bg[j][kh], acc[i][j], 0, 0, 0);
        __builtin_amdgcn_s_setprio(0);
        asm volatile("" ::: "memory");
        __builtin_amdgcn_s_barrier();
        asm volatile("" ::: "memory");

        // ---------- phase 1 : up half ----------
#pragma unroll
        for (int kh = 0; kh < 2; ++kh) {
            const int swoff = (((lane >> 4) + kh * 4) ^ sw7) * 8;
#pragma unroll
            for (int j = 0; j < 2; ++j)
                bu[j][kh] = *reinterpret_cast<const bf16x8*>(&Lc[(256 + wc * 32 + j * 16 + rlo) * 64 + swoff]);
        }
        if (kt + 2 < NKT) {
            ST_AG(Lc, (kt + 2) * 64);                          // A,G regions of Lc dead after ph0
            asm volatile("s_waitcnt vmcnt(4)" ::: "memory");   // keep only A,G(t+2) in flight
        } else {
            asm volatile("s_waitcnt vmcnt(0)" ::: "memory");   // epilogue drain
        }
        asm volatile("" ::: "memory");
        __builtin_amdgcn_s_barrier();
        asm volatile("s_waitcnt lgkmcnt(0)" ::: "memory");
        __builtin_amdgcn_s_setprio(1);
#pragma unroll
        for (int kh = 0; kh < 2; ++kh)
#pragma unroll
            for (int i = 0; i < 4; ++i)
#pragma unroll
                for (int j = 0; j < 2; ++j)
                    acc[i][2 + j] = __builtin_amdgcn_mfma_f32_16x16x32_bf16(af[i][kh], bu[j][kh], acc[i][2 + j], 0, 0, 0);
        __builtin_amdgcn_s_setprio(0);
        asm volatile("" ::: "memory");
        __builtin_amdgcn_s_barrier();
        asm volatile("" ::: "memory");
    }
#undef ST_AG
#undef ST_U
#undef GLD

    // epilogue: silu(gate) * up -> H
    const int rbase = m0 + wr * 64 + ((lane >> 4) * 4);
    const int cbase = n0 + wc * 32 + (lane & 15);
#pragma unroll
    for (int i = 0; i < 4; ++i)
#pragma unroll
        for (int reg = 0; reg < 4; ++reg) {
            const int row = rbase + i * 16 + reg;
#pragma unroll
            for (int j = 0; j < 2; ++j) {
                const float g = acc[i][j][reg];
                const float u = acc[i][2 + j][reg];
                const float h = g / (1.0f + __expf(-g)) * u;
                H[(size_t)row * FFDIM + cbase + j * 16] = f2bf(h);
            }
        }
}

// ========== PHASE 2: 128x128 down-proj, split-K=2, BK=64, 2-deep vmcnt(8) (r15) ==========
__global__ __launch_bounds__(256, 2) void gemm_p2(
    const unsigned short* __restrict__ A,
    const unsigned short* __restrict__ Bd_v, const unsigned short* __restrict__ Bd_l,
    unsigned short* __restrict__ P,
    const int* __restrict__ counts)
{
    __shared__ unsigned short Ls[2][256 * 64];   // 64 KiB

    const int m0 = blockIdx.y * 128;
    const int padNv = counts[0], padTot = counts[1];
    if (m0 >= padTot) return;
    const unsigned short* B0 = (m0 >= padNv) ? Bd_l : Bd_v;

    const int tid  = threadIdx.x;
    const int wid  = tid >> 6;
    const int lane = tid & 63;
    const int wr   = wid >> 1;
    const int wc   = wid & 1;
    const int n0   = blockIdx.x * 128;
    const int kbase = blockIdx.z * (FFDIM / 2);

    constexpr int NI = 8;
    const unsigned short* src[NI];
    int loff[NI];
    const int cs = ((lane & 7) ^ (lane >> 3)) * 8;
#pragma unroll
    for (int i = 0; i < NI; ++i) {
        const int g = wid * 64 + i * 8 + (lane >> 3);   // 0..255
        const unsigned short* p = (g < 128)
            ? A + (size_t)(m0 + g) * FFDIM
            : B0 + (size_t)(n0 + g - 128) * FFDIM;
        src[i] = p + kbase + cs;
        loff[i] = (wid * 64 + i * 8) * 64;
    }

#define STAGE2(buf, kkt) do { \
    const int _c = (kkt) * 64; \
    _Pragma("unroll") \
    for (int i = 0; i < NI; ++i) \
        __builtin_amdgcn_global_load_lds((const GAS void*)(src[i] + _c), \
                                         (LAS void*)&Ls[buf][loff[i]], 16, 0, 0); \
} while (0)

    const int rlo = lane & 15;
    const int sw7 = rlo & 7;

    f32x4 acc[4][4];
#pragma unroll
    for (int i = 0; i < 4; ++i)
#pragma unroll
        for (int j = 0; j < 4; ++j)
            acc[i][j] = (f32x4){0.f, 0.f, 0.f, 0.f};

    STAGE2(0, 0);

    const int NKT = (FFDIM / 2) / 64;  // 32
    bf16x8 af[4], bf[4];
#pragma unroll 1
    for (int kt = 0; kt < NKT; ++kt) {
        const int cur = kt & 1;

        asm volatile("" ::: "memory");
        __builtin_amdgcn_s_barrier();      // prev readers of buf cur^1 done
        asm volatile("" ::: "memory");

        if (kt + 1 < NKT) {
            STAGE2(cur ^ 1, kt + 1);
            asm volatile("s_waitcnt vmcnt(8)" ::: "memory");  // own cur loads done
        } else {
            asm volatile("s_waitcnt vmcnt(0)" ::: "memory");
        }

        asm volatile("" ::: "memory");
        __builtin_amdgcn_s_barrier();      // all waves' cur loads visible
        asm volatile("" ::: "memory");

#pragma unroll
        for (int kh = 0; kh < 2; ++kh) {
            const int kc    = (lane >> 4) + kh * 4;
            const int swoff = (kc ^ sw7) * 8;
#pragma unroll
            for (int i = 0; i < 4; ++i)
                af[i] = *reinterpret_cast<const bf16x8*>(&Ls[cur][(wr * 64 + i * 16 + rlo) * 64 + swoff]);
#pragma unroll
            for (int j = 0; j < 4; ++j)
                bf[j] = *reinterpret_cast<const bf16x8*>(&Ls[cur][(128 + wc * 64 + j * 16 + rlo) * 64 + swoff]);

            __builtin_amdgcn_s_setprio(1);
#pragma unroll
            for (int i = 0; i < 4; ++i)
#pragma unroll
                for (int j = 0; j < 4; ++j)
                    acc[i][j] = __builtin_amdgcn_mfma_f32_16x16x32_bf16(af[i], bf[j], acc[i][j], 0, 0, 0);
            __builtin_amdgcn_s_setprio(0);
        }
    }
#undef STAGE2

    unsigned short* Pz = P + (size_t)blockIdx.z * MAXPAD * DIM;
    const int rbase = m0 + wr * 64 + ((lane >> 4) * 4);
    const int cin   = lane & 15;
#pragma unroll
    for (int i = 0; i < 4; ++i)
#pragma unroll
        for (int reg = 0; reg < 4; ++reg) {
            const int row = rbase + i * 16 + reg;
#pragma unroll
            for (int j = 0; j < 4; ++j)
                Pz[(size_t)row * DIM + n0 + wc * 64 + j * 16 + cin] = f2bf(acc[i][j][reg]);
        }
}

// ---------- reduce: out[src_of[row]] = f32(P0[row]) + f32(P1[row]) ----------
__global__ void reduce_kernel(const unsigned short* __restrict__ P,
                              const int* __restrict__ src_of,
                              float* __restrict__ O) {
    const int gid = blockIdx.x * 256 + threadIdx.x;   // MAXPAD*128 threads
    const int row = gid >> 7;
    const int c   = (gid & 127) * 8;
    const int src = src_of[row];
    if (src < 0) return;
    const us8 a = *reinterpret_cast<const us8*>(P + (size_t)row * DIM + c);
    const us8 b = *reinterpret_cast<const us8*>(P + (size_t)(MAXPAD + row) * DIM + c);
    float4 o0, o1;
    o0.x = bf2f(a.v[0]) + bf2f(b.v[0]);
    o0.y = bf2f(a.v[1]) + bf2f(b.v[1]);
    o0.z = bf2f(a.v[2]) + bf2f(b.v[2]);
    o0.w = bf2f(a.v[3]) + bf2f(b.v[3]);
    o1.x = bf2f(a.v[4]) + bf2f(b.v[4]);
    o1.y = bf2f(a.v[5]) + bf2f(b.v[5]);
    o1.z = bf2f(a.v[6]) + bf2f(b.v[6]);
    o1.w = bf2f(a.v[7]) + bf2f(b.v[7]);
    float* dst = O + (size_t)src * DIM + c;
    *reinterpret_cast<float4*>(dst)     = o0;
    *reinterpret_cast<float4*>(dst + 4) = o1;
}

extern "C" void kernel_launch(void* const* d_in, const int* in_sizes, int n_in,
                              void* d_out, int out_size, void* d_ws, size_t ws_size,
                              hipStream_t stream) {
    const float* hs = (const float*)d_in[0];
    const int*   tt = (const int*)d_in[1];
    const float* w_vg = (const float*)d_in[2];
    const float* w_vu = (const float*)d_in[3];
    const float* w_vd = (const float*)d_in[4];
    const float* w_lg = (const float*)d_in[5];
    const float* w_lu = (const float*)d_in[6];
    const float* w_ld = (const float*)d_in[7];
    float* out = (float*)d_out;
    char* ws = (char*)d_ws;

    const size_t MATB = (size_t)FFDIM * DIM * 2;             // 8 MiB
    const size_t XGB  = (size_t)MAXPAD * DIM * 2;            // 9.44 MB
    const size_t HSZ  = (size_t)MAXPAD * FFDIM * 2;          // 37.75 MB

    int* counts = (int*)ws;
    int* src_of = (int*)(ws + 64);
    unsigned short* Xg = (unsigned short*)(ws + 32768);

    const int NELEM = FFDIM * DIM;
    const size_t need_big = 32768 + XGB + 6 * MATB + HSZ;    // ~93 MiB

    scan_kernel<<<1, 1024, 0, stream>>>(tt, src_of, counts);
    gather_cast<<<MAXPAD * 128 / 256, 256, 0, stream>>>(hs, src_of, Xg);

    if (ws_size >= need_big) {
        // big layout: all 6 weights own slots; Part aliases dead gate/up region
        unsigned short* Wg_v = (unsigned short*)(ws + 32768 + XGB);
        unsigned short* Wu_v = (unsigned short*)(ws + 32768 + XGB + MATB);
        unsigned short* Wg_l = (unsigned short*)(ws + 32768 + XGB + MATB * 2);
        unsigned short* Wu_l = (unsigned short*)(ws + 32768 + XGB + MATB * 3);
        unsigned short* Wd_v = (unsigned short*)(ws + 32768 + XGB + MATB * 4);
        unsigned short* Wd_l = (unsigned short*)(ws + 32768 + XGB + MATB * 5);
        unsigned short* H    = (unsigned short*)(ws + 32768 + XGB + MATB * 6);
        unsigned short* Part = Wg_v;   // 18.9 MB over 32 MB dead-after-p1 region

        dim3 gc6(NELEM / 2048, 6);
        cast6_kernel<<<gc6, 256, 0, stream>>>(w_vg, w_vu, w_lg, w_lu, w_vd, w_ld,
                                              Wg_v, Wu_v, Wg_l, Wu_l, Wd_v, Wd_l);

        dim3 g1(FFDIM / 128, MAXPAD / 128);   // 32 x 36, 512 threads
        gemm_p1<<<g1, 512, 0, stream>>>(Xg, Wg_v, Wu_v, Wg_l, Wu_l, H, counts);

        dim3 g2(DIM / 128, MAXPAD / 128, 2);  // 8 x 36 x 2
        gemm_p2<<<g2, 256, 0, stream>>>(H, Wd_v, Wd_l, Part, counts);

        reduce_kernel<<<MAXPAD * 128 / 256, 256, 0, stream>>>(Part, src_of, out);
    } else {
        // fallback: r15 layout/order (Wd + Part alias dead regions)
        unsigned short* Wg_v = (unsigned short*)(ws + 32768 + XGB);
        unsigned short* Wu_v = (unsigned short*)(ws + 32768 + XGB + MATB);
        unsigned short* Wg_l = (unsigned short*)(ws + 32768 + XGB + MATB * 2);
        unsigned short* Wu_l = (unsigned short*)(ws + 32768 + XGB + MATB * 3);
        unsigned short* H    = (unsigned short*)(ws + 32768 + XGB + MATB * 4);
        unsigned short* Wd_v = (unsigned short*)(ws + 32768);
        unsigned short* Wd_l = (unsigned short*)(ws + 32768 + MATB);
        unsigned short* Part = (unsigned short*)(ws + 32768 + MATB * 2);

        dim3 gc4(NELEM / 2048, 4);
        cast4_kernel<<<gc4, 256, 0, stream>>>(w_vg, w_vu, w_lg, w_lu, Wg_v, Wu_v, Wg_l, Wu_l);

        dim3 g1(FFDIM / 128, MAXPAD / 128);
        gemm_p1<<<g1, 512, 0, stream>>>(Xg, Wg_v, Wu_v, Wg_l, Wu_l, H, counts);

        dim3 gc2(NELEM / 2048, 2);
        cast2_kernel<<<gc2, 256, 0, stream>>>(w_vd, w_ld, Wd_v, Wd_l);

        dim3 g2(DIM / 128, MAXPAD / 128, 2);
        gemm_p2<<<g2, 256, 0, stream>>>(H, Wd_v, Wd_l, Part, counts);

        reduce_kernel<<<MAXPAD * 128 / 256, 256, 0, stream>>>(Part, src_of, out);
    }
}